// Round 18
// baseline (436.547 us; speedup 1.0000x reference)
//
#include <hip/hip_runtime.h>

#define NN 50000
#define NE 800000
#define GB 391     // ceil(NN/128) gemm node-blocks
#define NBUK 196   // dst buckets (dst>>8)
#define PB 128     // partition blocks
#define CH 6250    // edges per partition block (PB*CH == NE)
#define HLEN (NBUK * PB)       // 25088
#define SAB (HLEN / 256)       // 98 scan blocks
#define GS64 25000             // sharded gather blocks, D=64 (2 halves)
#define GS128 50000            // sharded gather blocks, D=128 (4 quarters)

typedef __attribute__((ext_vector_type(8))) short short8v;
typedef __attribute__((ext_vector_type(4))) float float4v;

__device__ __forceinline__ int uni(int v) { return __builtin_amdgcn_readfirstlane(v); }
__device__ __forceinline__ unsigned short f2bf(float f) {
    unsigned u = __float_as_uint(f);
    return (unsigned short)((u + 0x7FFFu + ((u >> 16) & 1u)) >> 16);
}
__device__ __forceinline__ float bf2f(unsigned short h) {
    return __uint_as_float(((unsigned)h) << 16);
}

// ================= radix CSR build =================
__global__ __launch_bounds__(256) void hist_kernel(const int* __restrict__ dst,
                                                   int* __restrict__ H) {
    __shared__ int h[NBUK];
    const int t = threadIdx.x;
    const int b = blockIdx.x;
    if (t < NBUK) h[t] = 0;
    __syncthreads();
    const int e0 = b * CH;
    for (int i = t; i < CH; i += 256) {
        int e = e0 + i;
        if (e < NE) atomicAdd(&h[dst[e] >> 8], 1);
    }
    __syncthreads();
    if (t < NBUK) H[t * PB + b] = h[t];
}

__global__ __launch_bounds__(256) void scanA_kernel(const int* __restrict__ a,
                                                    int* __restrict__ part) {
    __shared__ int red[256];
    const int t = threadIdx.x;
    red[t] = a[blockIdx.x * 256 + t];
    __syncthreads();
#pragma unroll
    for (int d = 128; d > 0; d >>= 1) {
        if (t < d) red[t] += red[t + d];
        __syncthreads();
    }
    if (t == 0) part[blockIdx.x] = red[0];
}

__global__ __launch_bounds__(128) void scanB_kernel(int* __restrict__ part) {
    __shared__ int ps[128];
    const int t = threadIdx.x;
    ps[t] = (t < SAB) ? part[t] : 0;
    __syncthreads();
#pragma unroll
    for (int d = 1; d < 128; d <<= 1) {
        int v = (t >= d) ? ps[t - d] : 0;
        __syncthreads();
        ps[t] += v;
        __syncthreads();
    }
    if (t < SAB) part[t] = (t == 0) ? 0 : ps[t - 1];
}

__global__ __launch_bounds__(256) void scanC_kernel(int* __restrict__ a,
                                                    const int* __restrict__ part) {
    __shared__ int ps[256];
    const int t = threadIdx.x;
    const int i = blockIdx.x * 256 + t;
    const int c = a[i];
    ps[t] = c;
    __syncthreads();
#pragma unroll
    for (int d = 1; d < 256; d <<= 1) {
        int v = (t >= d) ? ps[t - d] : 0;
        __syncthreads();
        ps[t] += v;
        __syncthreads();
    }
    a[i] = part[blockIdx.x] + ps[t] - c;   // exclusive
}

__global__ __launch_bounds__(256) void partition_kernel(const int* __restrict__ src,
                                                        const int* __restrict__ dst,
                                                        const int* __restrict__ Hs,
                                                        unsigned* __restrict__ tmp) {
    __shared__ int cur[NBUK];
    const int t = threadIdx.x;
    const int b = blockIdx.x;
    if (t < NBUK) cur[t] = Hs[t * PB + b];
    __syncthreads();
    const int e0 = b * CH;
    for (int i = t; i < CH; i += 256) {
        int e = e0 + i;
        if (e < NE) {
            const int d = dst[e];
            const int k = d >> 8;
            const int pos = atomicAdd(&cur[k], 1);
            tmp[pos] = (unsigned)src[e] | ((unsigned)(d & 255) << 16);
        }
    }
}

__global__ __launch_bounds__(256) void finalize_kernel(const unsigned* __restrict__ tmp,
                                                       const int* __restrict__ Hs,
                                                       int* __restrict__ off,
                                                       int* __restrict__ cnt,
                                                       float* __restrict__ inv,
                                                       unsigned short* __restrict__ srcs) {
    __shared__ int hist[256];
    __shared__ int ps[256];
    __shared__ int cur[256];
    const int t = threadIdx.x;
    const int k = blockIdx.x;
    const int s0 = Hs[k * PB];
    const int end = (k == NBUK - 1) ? NE : Hs[(k + 1) * PB];
    const int m = end - s0;
    hist[t] = 0;
    __syncthreads();
    for (int i = t; i < m; i += 256) {
        atomicAdd(&hist[(tmp[s0 + i] >> 16) & 255], 1);
    }
    __syncthreads();
    const int c = hist[t];
    ps[t] = c;
    __syncthreads();
#pragma unroll
    for (int d = 1; d < 256; d <<= 1) {
        int v = (t >= d) ? ps[t - d] : 0;
        __syncthreads();
        ps[t] += v;
        __syncthreads();
    }
    const int ex = ps[t] - c;
    const int node = k * 256 + t;
    if (node < NN) {
        off[node] = s0 + ex;
        cnt[node] = c;
        inv[node] = 1.0f / (float)max(c, 1);
    }
    cur[t] = s0 + ex;
    __syncthreads();
    for (int i = t; i < m; i += 256) {
        const unsigned u = tmp[s0 + i];
        const int p = atomicAdd(&cur[(u >> 16) & 255], 1);
        srcs[p] = (unsigned short)(u & 0xFFFFu);
    }
}

// ================= XCD-sharded pull-gather mean aggregation =================
// Feature columns split into 32-col (64 B, line-aligned) shards; blockIdx%8 -> XCD
// round-robin pins each shard's table slice to a subset of XCDs so the 3.2 MB
// slice stays L2-resident. Wave = 1 dst node x 1 shard; half-wave per edge,
// each lane loads 1 ushort (col = 32*shard + (lane&31)).
// D=64: 2 shards (XCD 0-3 / 4-7). D=128: 4 shards (2 XCDs each).
// MODE: 0 = mean ; 1 = relu(pre + mean) ; 2 = pre + mean. DUALB: extra bf16 copy.
template<int D, int MODE, int DUALB>
__global__ __launch_bounds__(256) void gather_kernel(
    const unsigned short* __restrict__ yb, int ys, const unsigned short* __restrict__ srcs,
    const int* __restrict__ off, const int* __restrict__ cnt,
    const float* __restrict__ inv, const float* __restrict__ pre, int ps,
    float* __restrict__ out, int os, unsigned short* __restrict__ outb) {
    const int bid = (int)blockIdx.x;
    const int wid = threadIdx.x >> 6;
    const int lane = threadIdx.x & 63;
    int shard, j;
    if constexpr (D == 64) {
        shard = (bid & 7) >> 2;               // 0..1
        j = (bid >> 3) * 4 + (bid & 3);       // 0..12499
    } else {
        shard = (bid & 7) >> 1;               // 0..3
        j = (bid >> 3) * 2 + (bid & 1);       // 0..12499
    }
    const int w = j * 4 + wid;                // dst node
    if (w >= NN) return;
    const int o = uni(off[w]);
    const int n = uni(cnt[w]);
    const int h = lane >> 5;                  // half-wave edge id
    const int l = lane & 31;                  // column within shard
    const int col = shard * 32 + l;

    float a0 = 0.0f;
    int i = 0;
    for (; i + 8 <= n; i += 8) {
        int e0 = srcs[o + i + h];
        int e1 = srcs[o + i + 2 + h];
        int e2 = srcs[o + i + 4 + h];
        int e3 = srcs[o + i + 6 + h];
        a0 += bf2f(yb[(size_t)e0 * ys + col]);
        a0 += bf2f(yb[(size_t)e1 * ys + col]);
        a0 += bf2f(yb[(size_t)e2 * ys + col]);
        a0 += bf2f(yb[(size_t)e3 * ys + col]);
    }
    for (; i + 2 <= n; i += 2) {
        int e = srcs[o + i + h];
        a0 += bf2f(yb[(size_t)e * ys + col]);
    }
    if (i < n && h == 0) {
        int e = srcs[o + i];
        a0 += bf2f(yb[(size_t)e * ys + col]);
    }
    a0 += __shfl_xor(a0, 32, 64);
    if (h != 0) return;

    float r0 = a0 * inv[w];
    if constexpr (MODE != 0) r0 += pre[(size_t)w * ps + col];
    if constexpr (MODE == 1) r0 = fmaxf(r0, 0.0f);
    out[(size_t)w * os + col] = r0;
    if constexpr (DUALB) outb[(size_t)w * 64 + col] = f2bf(r0);
}

// ================= weight planes: fp32 -> bf16 hi/lo =================
struct WSrc { const float* p[8]; };

__global__ __launch_bounds__(256) void wplanes_kernel(WSrc S,
                                                      unsigned short* __restrict__ ph,
                                                      unsigned short* __restrict__ pl) {
    const int e = blockIdx.x * 256 + threadIdx.x;   // 0..16383
    const int seg = blockIdx.y;
    const int row = e >> 7, k = e & 127;
    float x;
    switch (seg) {
        case 0:  x = (row < 64) ? S.p[0][row * 128 + k] : S.p[1][(row - 64) * 128 + k]; break;
        case 1:  x = (k < 64)   ? S.p[2][row * 64 + k]  : S.p[3][row * 64 + (k - 64)];  break;
        case 2:  x = S.p[4][e]; break;
        case 3:  x = S.p[5][e]; break;
        default: x = (row < 64) ? S.p[6][row * 128 + k] : S.p[7][(row - 64) * 128 + k]; break;
    }
    const unsigned u = __float_as_uint(x);
    const float lo = x - __uint_as_float(u & 0xFFFF0000u);
    const int o = seg * 16384 + e;
    ph[o] = (unsigned short)(u >> 16);
    pl[o] = (unsigned short)(__float_as_uint(lo) >> 16);
}

// ================= MFMA split-bf16 GEMM (128 nodes x 128 cols / block) =================
__global__ __launch_bounds__(256) void gemm_mfma(
    const float* __restrict__ in,
    const unsigned short* __restrict__ Bh, const unsigned short* __restrict__ Bl,
    float* __restrict__ out0, const float* __restrict__ bias0, int os0, int obf0,
    float* __restrict__ out1, const float* __restrict__ bias1, int os1, int obf1,
    int relu) {
    const int t = threadIdx.x;
    const int lane = t & 63;
    const int wid = t >> 6;
    const int wn = wid & 1;
    const int wc = wid >> 1;
    const int l15 = lane & 15;
    const int lk = lane >> 4;
    const int nb = (int)blockIdx.x * 128 + wn * 64;

    float* const outp = wc ? out1 : out0;
    const float* const biasp = wc ? bias1 : bias0;
    const int os = wc ? os1 : os0;
    const int obf = wc ? obf1 : obf0;
    const unsigned short* const Bhp = Bh + (size_t)(wc * 64) * 128;
    const unsigned short* const Blp = Bl + (size_t)(wc * 64) * 128;
    const ptrdiff_t dlo = Blp - Bhp;

    float4v acc[4][4];
#pragma unroll
    for (int mi = 0; mi < 4; ++mi)
#pragma unroll
        for (int ci = 0; ci < 4; ++ci) acc[mi][ci] = (float4v)0.0f;

    const float* arow[4];
#pragma unroll
    for (int mi = 0; mi < 4; ++mi) {
        int r = nb + mi * 16 + l15;
        if (r > NN - 1) r = NN - 1;
        arow[mi] = in + (size_t)r * 128;
    }
    const unsigned short* brow[4];
#pragma unroll
    for (int ci = 0; ci < 4; ++ci) brow[ci] = Bhp + (size_t)(ci * 16 + l15) * 128;

    for (int ks = 0; ks < 4; ++ks) {
        const int ko = ks * 32 + lk * 8;
        short8v Ah[4], Al[4];
#pragma unroll
        for (int mi = 0; mi < 4; ++mi) {
            const float4v v0 = *reinterpret_cast<const float4v*>(arow[mi] + ko);
            const float4v v1 = *reinterpret_cast<const float4v*>(arow[mi] + ko + 4);
            float xv[8] = {v0.x, v0.y, v0.z, v0.w, v1.x, v1.y, v1.z, v1.w};
            union { unsigned u[4]; short8v s; } H, L;
#pragma unroll
            for (int q = 0; q < 4; ++q) {
                const unsigned u0 = __float_as_uint(xv[2 * q]);
                const unsigned u1 = __float_as_uint(xv[2 * q + 1]);
                const float l0 = xv[2 * q]     - __uint_as_float(u0 & 0xFFFF0000u);
                const float l1 = xv[2 * q + 1] - __uint_as_float(u1 & 0xFFFF0000u);
                H.u[q] = (u1 & 0xFFFF0000u) | (u0 >> 16);
                L.u[q] = (__float_as_uint(l1) & 0xFFFF0000u) | (__float_as_uint(l0) >> 16);
            }
            Ah[mi] = H.s;
            Al[mi] = L.s;
        }
        short8v Bhf[4], Blf[4];
#pragma unroll
        for (int ci = 0; ci < 4; ++ci) {
            Bhf[ci] = *reinterpret_cast<const short8v*>(brow[ci] + ko);
            Blf[ci] = *reinterpret_cast<const short8v*>(brow[ci] + dlo + ko);
        }
#pragma unroll
        for (int mi = 0; mi < 4; ++mi)
#pragma unroll
            for (int ci = 0; ci < 4; ++ci) {
                acc[mi][ci] = __builtin_amdgcn_mfma_f32_16x16x32_bf16(Ah[mi], Bhf[ci], acc[mi][ci], 0, 0, 0);
                acc[mi][ci] = __builtin_amdgcn_mfma_f32_16x16x32_bf16(Ah[mi], Blf[ci], acc[mi][ci], 0, 0, 0);
                acc[mi][ci] = __builtin_amdgcn_mfma_f32_16x16x32_bf16(Al[mi], Bhf[ci], acc[mi][ci], 0, 0, 0);
            }
    }

#pragma unroll
    for (int ci = 0; ci < 4; ++ci) {
        const int c = ci * 16 + l15;
        const float b = biasp ? biasp[c] : 0.0f;
#pragma unroll
        for (int mi = 0; mi < 4; ++mi) {
#pragma unroll
            for (int j = 0; j < 4; ++j) {
                const int r = nb + mi * 16 + lk * 4 + j;
                if (r < NN) {
                    float v = acc[mi][ci][j] + b;
                    if (relu) v = fmaxf(v, 0.0f);
                    if (obf) ((unsigned short*)outp)[(size_t)r * os + c] = f2bf(v);
                    else outp[(size_t)r * os + c] = v;
                }
            }
        }
    }
}

extern "C" void kernel_launch(void* const* d_in, const int* in_sizes, int n_in,
                              void* d_out, int out_size, void* d_ws, size_t ws_size,
                              hipStream_t stream) {
    const float* x   = (const float*)d_in[0];
    const int*   eix = (const int*)d_in[1];
    const float* Wl1 = (const float*)d_in[2];
    const float* bl1 = (const float*)d_in[3];
    const float* Wr1 = (const float*)d_in[4];
    const float* Wl2 = (const float*)d_in[5];
    const float* bl2 = (const float*)d_in[6];
    const float* Wr2 = (const float*)d_in[7];
    const float* Wl3 = (const float*)d_in[8];
    const float* bl3 = (const float*)d_in[9];
    const float* Wr3 = (const float*)d_in[10];
    const float* Wl4 = (const float*)d_in[11];
    const float* bl4 = (const float*)d_in[12];
    const float* Wr4 = (const float*)d_in[13];
    float* out = (float*)d_out;

    const int* src = eix;        // edge_index[0]
    const int* dst = eix + NE;   // edge_index[1]

    // workspace layout (R12/R13-proven)
    char* ws = (char*)d_ws;
    int*   cnt  = (int*)ws;                          // [NN]
    int*   off  = cnt + NN;                          // [NN]
    float* inv  = (float*)(off + NN);                // [NN]
    int*   Hs   = (int*)(inv + NN);                  // [HLEN]
    int*   part = Hs + HLEN;                         // [256]
    unsigned short* srcs = (unsigned short*)(part + 256);  // [NE]
    unsigned short* ph = srcs + NE;                  // [81920]
    unsigned short* pl = ph + 81920;                 // [81920]
    unsigned short* XB1 = pl + 81920;                // [NN*64] bf16 msgs L1
    unsigned short* H1B = XB1 + (size_t)NN * 64;     // [NN*64] bf16 h1
    unsigned short* G3B = XB1;                       // alias [NN*128] bf16 msgs L3
    float* HCAT = (float*)(XB1 + (size_t)NN * 128);  // [NN*128] [mean|h1]; G4B alias
    float* H2   = HCAT + (size_t)NN * 128;           // [NN*128]
    float* HPRE = H2 + (size_t)NN * 128;             // [NN*128] h3pre/h3; tmp alias
    unsigned*       tmp = (unsigned*)HPRE;           // [NE] (CSR build only)
    unsigned short* G4B = (unsigned short*)HCAT;     // [NN*64] bf16 msgs L4

    // ---- radix CSR build ----
    hist_kernel<<<PB, 256, 0, stream>>>(dst, Hs);
    scanA_kernel<<<SAB, 256, 0, stream>>>(Hs, part);
    scanB_kernel<<<1, 128, 0, stream>>>(part);
    scanC_kernel<<<SAB, 256, 0, stream>>>(Hs, part);
    partition_kernel<<<PB, 256, 0, stream>>>(src, dst, Hs, tmp);
    finalize_kernel<<<NBUK, 256, 0, stream>>>(tmp, Hs, off, cnt, inv, srcs);

    // ---- weight bf16 hi/lo planes ----
    {
        WSrc s;
        s.p[0] = Wl1; s.p[1] = Wr1; s.p[2] = Wl2; s.p[3] = Wr2;
        s.p[4] = Wl3; s.p[5] = Wr3; s.p[6] = Wl4; s.p[7] = Wr4;
        wplanes_kernel<<<dim3(64, 5), 256, 0, stream>>>(s, ph, pl);
    }

    // ---- Layer 1: x@[Wl1;Wr1] -> XB1(bf16), h1pre(=HCAT+64 fp32, +bl1) ----
    gemm_mfma<<<GB, 256, 0, stream>>>(x, ph, pl,
                                      (float*)XB1, nullptr, 64, 1,
                                      HCAT + 64, bl1, 128, 0, 0);
    gather_kernel<64, 1, 1><<<GS64, 256, 0, stream>>>(
        XB1, 64, srcs, off, cnt, inv, HCAT + 64, 128, HCAT + 64, 128, H1B);

    // ---- Layer 2: mean(H1B) -> HCAT cols 0..63; [mean|h1]@[Wl2|Wr2] -> H2 (relu) ----
    gather_kernel<64, 0, 0><<<GS64, 256, 0, stream>>>(
        H1B, 64, srcs, off, cnt, inv, nullptr, 0, HCAT, 128, nullptr);
    gemm_mfma<<<GB, 256, 0, stream>>>(HCAT, ph + 16384, pl + 16384,
                                      H2, bl2, 128, 0,
                                      H2 + 64, bl2 + 64, 128, 0, 1);

    // ---- Layer 3: h2@Wl3 -> G3B (bf16); h2@Wr3+bl3 -> h3pre(=HPRE fp32) ----
    gemm_mfma<<<GB, 256, 0, stream>>>(H2, ph + 2 * 16384, pl + 2 * 16384,
                                      (float*)G3B, nullptr, 128, 1,
                                      (float*)(G3B + 64), nullptr, 128, 1, 0);
    gemm_mfma<<<GB, 256, 0, stream>>>(H2, ph + 3 * 16384, pl + 3 * 16384,
                                      HPRE, bl3, 128, 0,
                                      HPRE + 64, bl3 + 64, 128, 0, 0);
    gather_kernel<128, 1, 0><<<GS128, 256, 0, stream>>>(
        G3B, 128, srcs, off, cnt, inv, HPRE, 128, HPRE, 128, nullptr);

    // ---- Layer 4: h3@Wl4 -> G4B (bf16); h3@Wr4+bl4 -> d_out; gather -> out ----
    gemm_mfma<<<GB, 256, 0, stream>>>(HPRE, ph + 4 * 16384, pl + 4 * 16384,
                                      (float*)G4B, nullptr, 64, 1,
                                      out, bl4, 64, 0, 0);
    gather_kernel<64, 2, 0><<<GS64, 256, 0, stream>>>(
        G4B, 64, srcs, off, cnt, inv, out, 64, out, 64, nullptr);
}

// Round 19
// 345.949 us; speedup vs baseline: 1.2619x; 1.2619x over previous
//
#include <hip/hip_runtime.h>

#define NN 50000
#define NE 800000
#define GB 391     // ceil(NN/128) gemm node-blocks
#define NBUK 196   // dst buckets (dst>>8)
#define PB 128     // partition blocks
#define CH 6250    // edges per partition block (PB*CH == NE)
#define HLEN (NBUK * PB)       // 25088
#define SAB (HLEN / 256)       // 98 scan blocks

typedef __attribute__((ext_vector_type(8))) short short8v;
typedef __attribute__((ext_vector_type(4))) float float4v;
typedef __attribute__((ext_vector_type(2))) float float2v;

__device__ __forceinline__ int uni(int v) { return __builtin_amdgcn_readfirstlane(v); }
__device__ __forceinline__ unsigned short f2bf(float f) {
    unsigned u = __float_as_uint(f);
    return (unsigned short)((u + 0x7FFFu + ((u >> 16) & 1u)) >> 16);
}
__device__ __forceinline__ float bf2f(unsigned short h) {
    return __uint_as_float(((unsigned)h) << 16);
}

// ================= radix CSR build =================
__global__ __launch_bounds__(256) void hist_kernel(const int* __restrict__ dst,
                                                   int* __restrict__ H) {
    __shared__ int h[NBUK];
    const int t = threadIdx.x;
    const int b = blockIdx.x;
    if (t < NBUK) h[t] = 0;
    __syncthreads();
    const int e0 = b * CH;
    for (int i = t; i < CH; i += 256) {
        int e = e0 + i;
        if (e < NE) atomicAdd(&h[dst[e] >> 8], 1);
    }
    __syncthreads();
    if (t < NBUK) H[t * PB + b] = h[t];
}

__global__ __launch_bounds__(256) void scanA_kernel(const int* __restrict__ a,
                                                    int* __restrict__ part) {
    __shared__ int red[256];
    const int t = threadIdx.x;
    red[t] = a[blockIdx.x * 256 + t];
    __syncthreads();
#pragma unroll
    for (int d = 128; d > 0; d >>= 1) {
        if (t < d) red[t] += red[t + d];
        __syncthreads();
    }
    if (t == 0) part[blockIdx.x] = red[0];
}

__global__ __launch_bounds__(128) void scanB_kernel(int* __restrict__ part) {
    __shared__ int ps[128];
    const int t = threadIdx.x;
    ps[t] = (t < SAB) ? part[t] : 0;
    __syncthreads();
#pragma unroll
    for (int d = 1; d < 128; d <<= 1) {
        int v = (t >= d) ? ps[t - d] : 0;
        __syncthreads();
        ps[t] += v;
        __syncthreads();
    }
    if (t < SAB) part[t] = (t == 0) ? 0 : ps[t - 1];
}

__global__ __launch_bounds__(256) void scanC_kernel(int* __restrict__ a,
                                                    const int* __restrict__ part) {
    __shared__ int ps[256];
    const int t = threadIdx.x;
    const int i = blockIdx.x * 256 + t;
    const int c = a[i];
    ps[t] = c;
    __syncthreads();
#pragma unroll
    for (int d = 1; d < 256; d <<= 1) {
        int v = (t >= d) ? ps[t - d] : 0;
        __syncthreads();
        ps[t] += v;
        __syncthreads();
    }
    a[i] = part[blockIdx.x] + ps[t] - c;   // exclusive
}

__global__ __launch_bounds__(256) void partition_kernel(const int* __restrict__ src,
                                                        const int* __restrict__ dst,
                                                        const int* __restrict__ Hs,
                                                        unsigned* __restrict__ tmp) {
    __shared__ int cur[NBUK];
    const int t = threadIdx.x;
    const int b = blockIdx.x;
    if (t < NBUK) cur[t] = Hs[t * PB + b];
    __syncthreads();
    const int e0 = b * CH;
    for (int i = t; i < CH; i += 256) {
        int e = e0 + i;
        if (e < NE) {
            const int d = dst[e];
            const int k = d >> 8;
            const int pos = atomicAdd(&cur[k], 1);
            tmp[pos] = (unsigned)src[e] | ((unsigned)(d & 255) << 16);
        }
    }
}

__global__ __launch_bounds__(256) void finalize_kernel(const unsigned* __restrict__ tmp,
                                                       const int* __restrict__ Hs,
                                                       int* __restrict__ off,
                                                       int* __restrict__ cnt,
                                                       float* __restrict__ inv,
                                                       unsigned short* __restrict__ srcs) {
    __shared__ int hist[256];
    __shared__ int ps[256];
    __shared__ int cur[256];
    const int t = threadIdx.x;
    const int k = blockIdx.x;
    const int s0 = Hs[k * PB];
    const int end = (k == NBUK - 1) ? NE : Hs[(k + 1) * PB];
    const int m = end - s0;
    hist[t] = 0;
    __syncthreads();
    for (int i = t; i < m; i += 256) {
        atomicAdd(&hist[(tmp[s0 + i] >> 16) & 255], 1);
    }
    __syncthreads();
    const int c = hist[t];
    ps[t] = c;
    __syncthreads();
#pragma unroll
    for (int d = 1; d < 256; d <<= 1) {
        int v = (t >= d) ? ps[t - d] : 0;
        __syncthreads();
        ps[t] += v;
        __syncthreads();
    }
    const int ex = ps[t] - c;
    const int node = k * 256 + t;
    if (node < NN) {
        off[node] = s0 + ex;
        cnt[node] = c;
        inv[node] = 1.0f / (float)max(c, 1);
    }
    cur[t] = s0 + ex;
    __syncthreads();
    for (int i = t; i < m; i += 256) {
        const unsigned u = tmp[s0 + i];
        const int p = atomicAdd(&cur[(u >> 16) & 255], 1);
        srcs[p] = (unsigned short)(u & 0xFFFFu);
    }
}

// ================= pull-gather mean aggregation (half-wave per edge) =================
// bf16 tables temporal (L2 reuse); srcs/pre NT (read-once). NTOUT: NT final store (L4).
// MODE: 0 = mean ; 1 = relu(pre + mean) ; 2 = pre + mean. DUALB: extra bf16 copy (D=64).
template<int D, int MODE, int DUALB, int NTOUT>
__global__ __launch_bounds__(256) void gather_kernel(
    const unsigned short* __restrict__ yb, int ys, const unsigned short* __restrict__ srcs,
    const int* __restrict__ off, const int* __restrict__ cnt,
    const float* __restrict__ inv, const float* __restrict__ pre, int ps,
    float* __restrict__ out, int os, unsigned short* __restrict__ outb) {
    const int w = (blockIdx.x * blockDim.x + threadIdx.x) >> 6;
    const int lane = threadIdx.x & 63;
    if (w >= NN) return;
    const int o = uni(off[w]);
    const int n = uni(cnt[w]);
    const int h = lane >> 5;       // half-wave id
    const int l = lane & 31;

    float a0 = 0.0f, a1 = 0.0f, a2 = 0.0f, a3 = 0.0f;
    int i = 0;
    for (; i + 8 <= n; i += 8) {
        int e0 = __builtin_nontemporal_load(&srcs[o + i + h]);
        int e1 = __builtin_nontemporal_load(&srcs[o + i + 2 + h]);
        int e2 = __builtin_nontemporal_load(&srcs[o + i + 4 + h]);
        int e3 = __builtin_nontemporal_load(&srcs[o + i + 6 + h]);
        if constexpr (D == 64) {
            const ushort2 v0 = *reinterpret_cast<const ushort2*>(&yb[(size_t)e0 * ys + 2 * l]);
            const ushort2 v1 = *reinterpret_cast<const ushort2*>(&yb[(size_t)e1 * ys + 2 * l]);
            const ushort2 v2 = *reinterpret_cast<const ushort2*>(&yb[(size_t)e2 * ys + 2 * l]);
            const ushort2 v3 = *reinterpret_cast<const ushort2*>(&yb[(size_t)e3 * ys + 2 * l]);
            a0 += bf2f(v0.x) + bf2f(v1.x) + bf2f(v2.x) + bf2f(v3.x);
            a1 += bf2f(v0.y) + bf2f(v1.y) + bf2f(v2.y) + bf2f(v3.y);
        } else {
            const ushort4 v0 = *reinterpret_cast<const ushort4*>(&yb[(size_t)e0 * ys + 4 * l]);
            const ushort4 v1 = *reinterpret_cast<const ushort4*>(&yb[(size_t)e1 * ys + 4 * l]);
            const ushort4 v2 = *reinterpret_cast<const ushort4*>(&yb[(size_t)e2 * ys + 4 * l]);
            const ushort4 v3 = *reinterpret_cast<const ushort4*>(&yb[(size_t)e3 * ys + 4 * l]);
            a0 += bf2f(v0.x) + bf2f(v1.x) + bf2f(v2.x) + bf2f(v3.x);
            a1 += bf2f(v0.y) + bf2f(v1.y) + bf2f(v2.y) + bf2f(v3.y);
            a2 += bf2f(v0.z) + bf2f(v1.z) + bf2f(v2.z) + bf2f(v3.z);
            a3 += bf2f(v0.w) + bf2f(v1.w) + bf2f(v2.w) + bf2f(v3.w);
        }
    }
    for (; i + 2 <= n; i += 2) {
        int e = __builtin_nontemporal_load(&srcs[o + i + h]);
        if constexpr (D == 64) {
            const ushort2 v = *reinterpret_cast<const ushort2*>(&yb[(size_t)e * ys + 2 * l]);
            a0 += bf2f(v.x);
            a1 += bf2f(v.y);
        } else {
            const ushort4 v = *reinterpret_cast<const ushort4*>(&yb[(size_t)e * ys + 4 * l]);
            a0 += bf2f(v.x); a1 += bf2f(v.y); a2 += bf2f(v.z); a3 += bf2f(v.w);
        }
    }
    if (i < n && h == 0) {
        int e = __builtin_nontemporal_load(&srcs[o + i]);
        if constexpr (D == 64) {
            const ushort2 v = *reinterpret_cast<const ushort2*>(&yb[(size_t)e * ys + 2 * l]);
            a0 += bf2f(v.x);
            a1 += bf2f(v.y);
        } else {
            const ushort4 v = *reinterpret_cast<const ushort4*>(&yb[(size_t)e * ys + 4 * l]);
            a0 += bf2f(v.x); a1 += bf2f(v.y); a2 += bf2f(v.z); a3 += bf2f(v.w);
        }
    }
    // combine halves
    a0 += __shfl_xor(a0, 32, 64);
    a1 += __shfl_xor(a1, 32, 64);
    if constexpr (D == 128) {
        a2 += __shfl_xor(a2, 32, 64);
        a3 += __shfl_xor(a3, 32, 64);
    }
    if (h != 0) return;

    const float iv = inv[w];
    if constexpr (D == 64) {
        float r0 = a0 * iv, r1 = a1 * iv;
        if constexpr (MODE != 0) {
            const float2v pv = __builtin_nontemporal_load(
                reinterpret_cast<const float2v*>(&pre[(size_t)w * ps + 2 * l]));
            r0 += pv.x; r1 += pv.y;
        }
        if constexpr (MODE == 1) { r0 = fmaxf(r0, 0.0f); r1 = fmaxf(r1, 0.0f); }
        float2v sv = {r0, r1};
        float2v* op = reinterpret_cast<float2v*>(&out[(size_t)w * os + 2 * l]);
        if constexpr (NTOUT) __builtin_nontemporal_store(sv, op);
        else *op = sv;
        if constexpr (DUALB) {
            ushort2 bv = {f2bf(r0), f2bf(r1)};
            *reinterpret_cast<ushort2*>(&outb[(size_t)w * 64 + 2 * l]) = bv;
        }
    } else {
        float r0 = a0 * iv, r1 = a1 * iv, r2 = a2 * iv, r3 = a3 * iv;
        if constexpr (MODE != 0) {
            const float4v pv = __builtin_nontemporal_load(
                reinterpret_cast<const float4v*>(&pre[(size_t)w * ps + 4 * l]));
            r0 += pv.x; r1 += pv.y; r2 += pv.z; r3 += pv.w;
        }
        if constexpr (MODE == 1) {
            r0 = fmaxf(r0, 0.0f); r1 = fmaxf(r1, 0.0f);
            r2 = fmaxf(r2, 0.0f); r3 = fmaxf(r3, 0.0f);
        }
        float4v sv = {r0, r1, r2, r3};
        float4v* op = reinterpret_cast<float4v*>(&out[(size_t)w * os + 4 * l]);
        if constexpr (NTOUT) __builtin_nontemporal_store(sv, op);
        else *op = sv;
    }
}

// ================= weight planes: fp32 -> bf16 hi/lo =================
struct WSrc { const float* p[8]; };

__global__ __launch_bounds__(256) void wplanes_kernel(WSrc S,
                                                      unsigned short* __restrict__ ph,
                                                      unsigned short* __restrict__ pl) {
    const int e = blockIdx.x * 256 + threadIdx.x;   // 0..16383
    const int seg = blockIdx.y;
    const int row = e >> 7, k = e & 127;
    float x;
    switch (seg) {
        case 0:  x = (row < 64) ? S.p[0][row * 128 + k] : S.p[1][(row - 64) * 128 + k]; break;
        case 1:  x = (k < 64)   ? S.p[2][row * 64 + k]  : S.p[3][row * 64 + (k - 64)];  break;
        case 2:  x = S.p[4][e]; break;
        case 3:  x = S.p[5][e]; break;
        default: x = (row < 64) ? S.p[6][row * 128 + k] : S.p[7][(row - 64) * 128 + k]; break;
    }
    const unsigned u = __float_as_uint(x);
    const float lo = x - __uint_as_float(u & 0xFFFF0000u);
    const int o = seg * 16384 + e;
    ph[o] = (unsigned short)(u >> 16);
    pl[o] = (unsigned short)(__float_as_uint(lo) >> 16);
}

// ================= MFMA split-bf16 GEMM (128 nodes x 128 cols / block) =================
// R12-proven geometry; ks loop fully unrolled for ILP (grid-limited occupancy).
__global__ __launch_bounds__(256) void gemm_mfma(
    const float* __restrict__ in,
    const unsigned short* __restrict__ Bh, const unsigned short* __restrict__ Bl,
    float* __restrict__ out0, const float* __restrict__ bias0, int os0, int obf0,
    float* __restrict__ out1, const float* __restrict__ bias1, int os1, int obf1,
    int relu) {
    const int t = threadIdx.x;
    const int lane = t & 63;
    const int wid = t >> 6;
    const int wn = wid & 1;
    const int wc = wid >> 1;
    const int l15 = lane & 15;
    const int lk = lane >> 4;
    const int nb = (int)blockIdx.x * 128 + wn * 64;

    float* const outp = wc ? out1 : out0;
    const float* const biasp = wc ? bias1 : bias0;
    const int os = wc ? os1 : os0;
    const int obf = wc ? obf1 : obf0;
    const unsigned short* const Bhp = Bh + (size_t)(wc * 64) * 128;
    const unsigned short* const Blp = Bl + (size_t)(wc * 64) * 128;
    const ptrdiff_t dlo = Blp - Bhp;

    float4v acc[4][4];
#pragma unroll
    for (int mi = 0; mi < 4; ++mi)
#pragma unroll
        for (int ci = 0; ci < 4; ++ci) acc[mi][ci] = (float4v)0.0f;

    const float* arow[4];
#pragma unroll
    for (int mi = 0; mi < 4; ++mi) {
        int r = nb + mi * 16 + l15;
        if (r > NN - 1) r = NN - 1;
        arow[mi] = in + (size_t)r * 128;
    }
    const unsigned short* brow[4];
#pragma unroll
    for (int ci = 0; ci < 4; ++ci) brow[ci] = Bhp + (size_t)(ci * 16 + l15) * 128;

#pragma unroll
    for (int ks = 0; ks < 4; ++ks) {
        const int ko = ks * 32 + lk * 8;
        short8v Ah[4], Al[4];
#pragma unroll
        for (int mi = 0; mi < 4; ++mi) {
            const float4v v0 = *reinterpret_cast<const float4v*>(arow[mi] + ko);
            const float4v v1 = *reinterpret_cast<const float4v*>(arow[mi] + ko + 4);
            float xv[8] = {v0.x, v0.y, v0.z, v0.w, v1.x, v1.y, v1.z, v1.w};
            union { unsigned u[4]; short8v s; } H, L;
#pragma unroll
            for (int q = 0; q < 4; ++q) {
                const unsigned u0 = __float_as_uint(xv[2 * q]);
                const unsigned u1 = __float_as_uint(xv[2 * q + 1]);
                const float l0 = xv[2 * q]     - __uint_as_float(u0 & 0xFFFF0000u);
                const float l1 = xv[2 * q + 1] - __uint_as_float(u1 & 0xFFFF0000u);
                H.u[q] = (u1 & 0xFFFF0000u) | (u0 >> 16);
                L.u[q] = (__float_as_uint(l1) & 0xFFFF0000u) | (__float_as_uint(l0) >> 16);
            }
            Ah[mi] = H.s;
            Al[mi] = L.s;
        }
        short8v Bhf[4], Blf[4];
#pragma unroll
        for (int ci = 0; ci < 4; ++ci) {
            Bhf[ci] = *reinterpret_cast<const short8v*>(brow[ci] + ko);
            Blf[ci] = *reinterpret_cast<const short8v*>(brow[ci] + dlo + ko);
        }
#pragma unroll
        for (int mi = 0; mi < 4; ++mi)
#pragma unroll
            for (int ci = 0; ci < 4; ++ci) {
                acc[mi][ci] = __builtin_amdgcn_mfma_f32_16x16x32_bf16(Ah[mi], Bhf[ci], acc[mi][ci], 0, 0, 0);
                acc[mi][ci] = __builtin_amdgcn_mfma_f32_16x16x32_bf16(Ah[mi], Blf[ci], acc[mi][ci], 0, 0, 0);
                acc[mi][ci] = __builtin_amdgcn_mfma_f32_16x16x32_bf16(Al[mi], Bhf[ci], acc[mi][ci], 0, 0, 0);
            }
    }

#pragma unroll
    for (int ci = 0; ci < 4; ++ci) {
        const int c = ci * 16 + l15;
        const float b = biasp ? biasp[c] : 0.0f;
#pragma unroll
        for (int mi = 0; mi < 4; ++mi) {
#pragma unroll
            for (int j = 0; j < 4; ++j) {
                const int r = nb + mi * 16 + lk * 4 + j;
                if (r < NN) {
                    float v = acc[mi][ci][j] + b;
                    if (relu) v = fmaxf(v, 0.0f);
                    if (obf) ((unsigned short*)outp)[(size_t)r * os + c] = f2bf(v);
                    else outp[(size_t)r * os + c] = v;
                }
            }
        }
    }
}

extern "C" void kernel_launch(void* const* d_in, const int* in_sizes, int n_in,
                              void* d_out, int out_size, void* d_ws, size_t ws_size,
                              hipStream_t stream) {
    const float* x   = (const float*)d_in[0];
    const int*   eix = (const int*)d_in[1];
    const float* Wl1 = (const float*)d_in[2];
    const float* bl1 = (const float*)d_in[3];
    const float* Wr1 = (const float*)d_in[4];
    const float* Wl2 = (const float*)d_in[5];
    const float* bl2 = (const float*)d_in[6];
    const float* Wr2 = (const float*)d_in[7];
    const float* Wl3 = (const float*)d_in[8];
    const float* bl3 = (const float*)d_in[9];
    const float* Wr3 = (const float*)d_in[10];
    const float* Wl4 = (const float*)d_in[11];
    const float* bl4 = (const float*)d_in[12];
    const float* Wr4 = (const float*)d_in[13];
    float* out = (float*)d_out;

    const int* src = eix;        // edge_index[0]
    const int* dst = eix + NE;   // edge_index[1]

    // workspace layout
    char* ws = (char*)d_ws;
    int*   cnt  = (int*)ws;                          // [NN]
    int*   off  = cnt + NN;                          // [NN]
    float* inv  = (float*)(off + NN);                // [NN]
    int*   Hs   = (int*)(inv + NN);                  // [HLEN]
    int*   part = Hs + HLEN;                         // [256]
    unsigned short* srcs = (unsigned short*)(part + 256);  // [NE]
    unsigned short* ph = srcs + NE;                  // [81920]
    unsigned short* pl = ph + 81920;                 // [81920]
    unsigned short* XB1 = pl + 81920;                // [NN*64] bf16 msgs L1
    unsigned short* H1B = XB1 + (size_t)NN * 64;     // [NN*64] bf16 h1
    unsigned short* G3B = XB1;                       // alias [NN*128] bf16 msgs L3
    float* HCAT = (float*)(XB1 + (size_t)NN * 128);  // [NN*128] [mean|h1]; G4B alias
    float* H2   = HCAT + (size_t)NN * 128;           // [NN*128]
    float* HPRE = H2 + (size_t)NN * 128;             // [NN*128] h3pre/h3; tmp alias
    unsigned*       tmp = (unsigned*)HPRE;           // [NE] (CSR build only)
    unsigned short* G4B = (unsigned short*)HCAT;     // [NN*64] bf16 msgs L4

    // ---- radix CSR build ----
    hist_kernel<<<PB, 256, 0, stream>>>(dst, Hs);
    scanA_kernel<<<SAB, 256, 0, stream>>>(Hs, part);
    scanB_kernel<<<1, 128, 0, stream>>>(part);
    scanC_kernel<<<SAB, 256, 0, stream>>>(Hs, part);
    partition_kernel<<<PB, 256, 0, stream>>>(src, dst, Hs, tmp);
    finalize_kernel<<<NBUK, 256, 0, stream>>>(tmp, Hs, off, cnt, inv, srcs);

    // ---- weight bf16 hi/lo planes ----
    {
        WSrc s;
        s.p[0] = Wl1; s.p[1] = Wr1; s.p[2] = Wl2; s.p[3] = Wr2;
        s.p[4] = Wl3; s.p[5] = Wr3; s.p[6] = Wl4; s.p[7] = Wr4;
        wplanes_kernel<<<dim3(64, 5), 256, 0, stream>>>(s, ph, pl);
    }

    // ---- Layer 1: x@[Wl1;Wr1] -> XB1(bf16), h1pre(=HCAT+64 fp32, +bl1) ----
    gemm_mfma<<<GB, 256, 0, stream>>>(x, ph, pl,
                                      (float*)XB1, nullptr, 64, 1,
                                      HCAT + 64, bl1, 128, 0, 0);
    gather_kernel<64, 1, 1, 0><<<12500, 256, 0, stream>>>(
        XB1, 64, srcs, off, cnt, inv, HCAT + 64, 128, HCAT + 64, 128, H1B);

    // ---- Layer 2: mean(H1B) -> HCAT cols 0..63; [mean|h1]@[Wl2|Wr2] -> H2 (relu) ----
    gather_kernel<64, 0, 0, 0><<<12500, 256, 0, stream>>>(
        H1B, 64, srcs, off, cnt, inv, nullptr, 0, HCAT, 128, nullptr);
    gemm_mfma<<<GB, 256, 0, stream>>>(HCAT, ph + 16384, pl + 16384,
                                      H2, bl2, 128, 0,
                                      H2 + 64, bl2 + 64, 128, 0, 1);

    // ---- Layer 3: h2@Wl3 -> G3B (bf16); h2@Wr3+bl3 -> h3pre(=HPRE fp32) ----
    gemm_mfma<<<GB, 256, 0, stream>>>(H2, ph + 2 * 16384, pl + 2 * 16384,
                                      (float*)G3B, nullptr, 128, 1,
                                      (float*)(G3B + 64), nullptr, 128, 1, 0);
    gemm_mfma<<<GB, 256, 0, stream>>>(H2, ph + 3 * 16384, pl + 3 * 16384,
                                      HPRE, bl3, 128, 0,
                                      HPRE + 64, bl3 + 64, 128, 0, 0);
    gather_kernel<128, 1, 0, 0><<<12500, 256, 0, stream>>>(
        G3B, 128, srcs, off, cnt, inv, HPRE, 128, HPRE, 128, nullptr);

    // ---- Layer 4: h3@Wl4 -> G4B (bf16); h3@Wr4+bl4 -> d_out; gather -> out (NT) ----
    gemm_mfma<<<GB, 256, 0, stream>>>(HPRE, ph + 4 * 16384, pl + 4 * 16384,
                                      (float*)G4B, nullptr, 64, 1,
                                      out, bl4, 64, 0, 0);
    gather_kernel<64, 2, 0, 1><<<12500, 256, 0, stream>>>(
        G4B, 64, srcs, off, cnt, inv, out, 64, out, 64, nullptr);
}

// Round 20
// 333.614 us; speedup vs baseline: 1.3085x; 1.0370x over previous
//
#include <hip/hip_runtime.h>

#define NN 50000
#define NE 800000
#define GB 391     // ceil(NN/128) gemm node-blocks
#define NBUK 196   // dst buckets (dst>>8)
#define PB 128     // partition blocks
#define CH 6250    // edges per partition block (PB*CH == NE)
#define HLEN (NBUK * PB)       // 25088
#define SAB (HLEN / 256)       // 98 scan blocks

typedef __attribute__((ext_vector_type(8))) short short8v;
typedef __attribute__((ext_vector_type(4))) float float4v;

__device__ __forceinline__ int uni(int v) { return __builtin_amdgcn_readfirstlane(v); }
__device__ __forceinline__ unsigned short f2bf(float f) {
    unsigned u = __float_as_uint(f);
    return (unsigned short)((u + 0x7FFFu + ((u >> 16) & 1u)) >> 16);
}
__device__ __forceinline__ float bf2f(unsigned short h) {
    return __uint_as_float(((unsigned)h) << 16);
}

// ================= radix CSR build =================
__global__ __launch_bounds__(256) void hist_kernel(const int* __restrict__ dst,
                                                   int* __restrict__ H) {
    __shared__ int h[NBUK];
    const int t = threadIdx.x;
    const int b = blockIdx.x;
    if (t < NBUK) h[t] = 0;
    __syncthreads();
    const int e0 = b * CH;
    for (int i = t; i < CH; i += 256) {
        int e = e0 + i;
        if (e < NE) atomicAdd(&h[dst[e] >> 8], 1);
    }
    __syncthreads();
    if (t < NBUK) H[t * PB + b] = h[t];
}

__global__ __launch_bounds__(256) void scanA_kernel(const int* __restrict__ a,
                                                    int* __restrict__ part) {
    __shared__ int red[256];
    const int t = threadIdx.x;
    red[t] = a[blockIdx.x * 256 + t];
    __syncthreads();
#pragma unroll
    for (int d = 128; d > 0; d >>= 1) {
        if (t < d) red[t] += red[t + d];
        __syncthreads();
    }
    if (t == 0) part[blockIdx.x] = red[0];
}

__global__ __launch_bounds__(128) void scanB_kernel(int* __restrict__ part) {
    __shared__ int ps[128];
    const int t = threadIdx.x;
    ps[t] = (t < SAB) ? part[t] : 0;
    __syncthreads();
#pragma unroll
    for (int d = 1; d < 128; d <<= 1) {
        int v = (t >= d) ? ps[t - d] : 0;
        __syncthreads();
        ps[t] += v;
        __syncthreads();
    }
    if (t < SAB) part[t] = (t == 0) ? 0 : ps[t - 1];
}

__global__ __launch_bounds__(256) void scanC_kernel(int* __restrict__ a,
                                                    const int* __restrict__ part) {
    __shared__ int ps[256];
    const int t = threadIdx.x;
    const int i = blockIdx.x * 256 + t;
    const int c = a[i];
    ps[t] = c;
    __syncthreads();
#pragma unroll
    for (int d = 1; d < 256; d <<= 1) {
        int v = (t >= d) ? ps[t - d] : 0;
        __syncthreads();
        ps[t] += v;
        __syncthreads();
    }
    a[i] = part[blockIdx.x] + ps[t] - c;   // exclusive
}

__global__ __launch_bounds__(256) void partition_kernel(const int* __restrict__ src,
                                                        const int* __restrict__ dst,
                                                        const int* __restrict__ Hs,
                                                        unsigned* __restrict__ tmp) {
    __shared__ int cur[NBUK];
    const int t = threadIdx.x;
    const int b = blockIdx.x;
    if (t < NBUK) cur[t] = Hs[t * PB + b];
    __syncthreads();
    const int e0 = b * CH;
    for (int i = t; i < CH; i += 256) {
        int e = e0 + i;
        if (e < NE) {
            const int d = dst[e];
            const int k = d >> 8;
            const int pos = atomicAdd(&cur[k], 1);
            tmp[pos] = (unsigned)src[e] | ((unsigned)(d & 255) << 16);
        }
    }
}

__global__ __launch_bounds__(256) void finalize_kernel(const unsigned* __restrict__ tmp,
                                                       const int* __restrict__ Hs,
                                                       int* __restrict__ off,
                                                       int* __restrict__ cnt,
                                                       float* __restrict__ inv,
                                                       int* __restrict__ srcs) {
    __shared__ int hist[256];
    __shared__ int ps[256];
    __shared__ int cur[256];
    const int t = threadIdx.x;
    const int k = blockIdx.x;
    const int s0 = Hs[k * PB];
    const int end = (k == NBUK - 1) ? NE : Hs[(k + 1) * PB];
    const int m = end - s0;
    hist[t] = 0;
    __syncthreads();
    for (int i = t; i < m; i += 256) {
        atomicAdd(&hist[(tmp[s0 + i] >> 16) & 255], 1);
    }
    __syncthreads();
    const int c = hist[t];
    ps[t] = c;
    __syncthreads();
#pragma unroll
    for (int d = 1; d < 256; d <<= 1) {
        int v = (t >= d) ? ps[t - d] : 0;
        __syncthreads();
        ps[t] += v;
        __syncthreads();
    }
    const int ex = ps[t] - c;
    const int node = k * 256 + t;
    if (node < NN) {
        off[node] = s0 + ex;
        cnt[node] = c;
        inv[node] = 1.0f / (float)max(c, 1);
    }
    cur[t] = s0 + ex;
    __syncthreads();
    for (int i = t; i < m; i += 256) {
        const unsigned u = tmp[s0 + i];
        const int p = atomicAdd(&cur[(u >> 16) & 255], 1);
        srcs[p] = (int)(u & 0xFFFFu);
    }
}

// ================= pull-gather mean aggregation (half-wave per edge, temporal) =================
// MODE: 0 = mean ; 1 = relu(pre + mean) ; 2 = pre + mean. DUALB: extra bf16 copy (D=64).
template<int D, int MODE, int DUALB>
__global__ __launch_bounds__(256) void gather_kernel(
    const unsigned short* __restrict__ yb, int ys, const int* __restrict__ srcs,
    const int* __restrict__ off, const int* __restrict__ cnt,
    const float* __restrict__ inv, const float* __restrict__ pre, int ps,
    float* __restrict__ out, int os, unsigned short* __restrict__ outb) {
    const int w = (blockIdx.x * blockDim.x + threadIdx.x) >> 6;
    const int lane = threadIdx.x & 63;
    if (w >= NN) return;
    const int o = uni(off[w]);
    const int n = uni(cnt[w]);
    const int h = lane >> 5;       // half-wave id
    const int l = lane & 31;

    float a0 = 0.0f, a1 = 0.0f, a2 = 0.0f, a3 = 0.0f;
    int i = 0;
    for (; i + 8 <= n; i += 8) {
        int e0 = srcs[o + i + h];
        int e1 = srcs[o + i + 2 + h];
        int e2 = srcs[o + i + 4 + h];
        int e3 = srcs[o + i + 6 + h];
        if constexpr (D == 64) {
            const ushort2 v0 = *reinterpret_cast<const ushort2*>(&yb[(size_t)e0 * ys + 2 * l]);
            const ushort2 v1 = *reinterpret_cast<const ushort2*>(&yb[(size_t)e1 * ys + 2 * l]);
            const ushort2 v2 = *reinterpret_cast<const ushort2*>(&yb[(size_t)e2 * ys + 2 * l]);
            const ushort2 v3 = *reinterpret_cast<const ushort2*>(&yb[(size_t)e3 * ys + 2 * l]);
            a0 += bf2f(v0.x) + bf2f(v1.x) + bf2f(v2.x) + bf2f(v3.x);
            a1 += bf2f(v0.y) + bf2f(v1.y) + bf2f(v2.y) + bf2f(v3.y);
        } else {
            const ushort4 v0 = *reinterpret_cast<const ushort4*>(&yb[(size_t)e0 * ys + 4 * l]);
            const ushort4 v1 = *reinterpret_cast<const ushort4*>(&yb[(size_t)e1 * ys + 4 * l]);
            const ushort4 v2 = *reinterpret_cast<const ushort4*>(&yb[(size_t)e2 * ys + 4 * l]);
            const ushort4 v3 = *reinterpret_cast<const ushort4*>(&yb[(size_t)e3 * ys + 4 * l]);
            a0 += bf2f(v0.x) + bf2f(v1.x) + bf2f(v2.x) + bf2f(v3.x);
            a1 += bf2f(v0.y) + bf2f(v1.y) + bf2f(v2.y) + bf2f(v3.y);
            a2 += bf2f(v0.z) + bf2f(v1.z) + bf2f(v2.z) + bf2f(v3.z);
            a3 += bf2f(v0.w) + bf2f(v1.w) + bf2f(v2.w) + bf2f(v3.w);
        }
    }
    for (; i + 2 <= n; i += 2) {
        int e = srcs[o + i + h];
        if constexpr (D == 64) {
            const ushort2 v = *reinterpret_cast<const ushort2*>(&yb[(size_t)e * ys + 2 * l]);
            a0 += bf2f(v.x);
            a1 += bf2f(v.y);
        } else {
            const ushort4 v = *reinterpret_cast<const ushort4*>(&yb[(size_t)e * ys + 4 * l]);
            a0 += bf2f(v.x); a1 += bf2f(v.y); a2 += bf2f(v.z); a3 += bf2f(v.w);
        }
    }
    if (i < n && h == 0) {
        int e = srcs[o + i];
        if constexpr (D == 64) {
            const ushort2 v = *reinterpret_cast<const ushort2*>(&yb[(size_t)e * ys + 2 * l]);
            a0 += bf2f(v.x);
            a1 += bf2f(v.y);
        } else {
            const ushort4 v = *reinterpret_cast<const ushort4*>(&yb[(size_t)e * ys + 4 * l]);
            a0 += bf2f(v.x); a1 += bf2f(v.y); a2 += bf2f(v.z); a3 += bf2f(v.w);
        }
    }
    // combine halves
    a0 += __shfl_xor(a0, 32, 64);
    a1 += __shfl_xor(a1, 32, 64);
    if constexpr (D == 128) {
        a2 += __shfl_xor(a2, 32, 64);
        a3 += __shfl_xor(a3, 32, 64);
    }
    if (h != 0) return;

    const float iv = inv[w];
    if constexpr (D == 64) {
        float r0 = a0 * iv, r1 = a1 * iv;
        if constexpr (MODE != 0) {
            const float2 pv = *reinterpret_cast<const float2*>(&pre[(size_t)w * ps + 2 * l]);
            r0 += pv.x; r1 += pv.y;
        }
        if constexpr (MODE == 1) { r0 = fmaxf(r0, 0.0f); r1 = fmaxf(r1, 0.0f); }
        float2 sv = {r0, r1};
        *reinterpret_cast<float2*>(&out[(size_t)w * os + 2 * l]) = sv;
        if constexpr (DUALB) {
            ushort2 bv = {f2bf(r0), f2bf(r1)};
            *reinterpret_cast<ushort2*>(&outb[(size_t)w * 64 + 2 * l]) = bv;
        }
    } else {
        float r0 = a0 * iv, r1 = a1 * iv, r2 = a2 * iv, r3 = a3 * iv;
        if constexpr (MODE != 0) {
            const float4 pv = *reinterpret_cast<const float4*>(&pre[(size_t)w * ps + 4 * l]);
            r0 += pv.x; r1 += pv.y; r2 += pv.z; r3 += pv.w;
        }
        if constexpr (MODE == 1) {
            r0 = fmaxf(r0, 0.0f); r1 = fmaxf(r1, 0.0f);
            r2 = fmaxf(r2, 0.0f); r3 = fmaxf(r3, 0.0f);
        }
        float4 sv = {r0, r1, r2, r3};
        *reinterpret_cast<float4*>(&out[(size_t)w * os + 4 * l]) = sv;
    }
}

// ================= weight planes: fp32 -> bf16 hi/lo =================
struct WSrc { const float* p[8]; };

__global__ __launch_bounds__(256) void wplanes_kernel(WSrc S,
                                                      unsigned short* __restrict__ ph,
                                                      unsigned short* __restrict__ pl) {
    const int e = blockIdx.x * 256 + threadIdx.x;   // 0..16383
    const int seg = blockIdx.y;
    const int row = e >> 7, k = e & 127;
    float x;
    switch (seg) {
        case 0:  x = (row < 64) ? S.p[0][row * 128 + k] : S.p[1][(row - 64) * 128 + k]; break;
        case 1:  x = (k < 64)   ? S.p[2][row * 64 + k]  : S.p[3][row * 64 + (k - 64)];  break;
        case 2:  x = S.p[4][e]; break;
        case 3:  x = S.p[5][e]; break;
        default: x = (row < 64) ? S.p[6][row * 128 + k] : S.p[7][(row - 64) * 128 + k]; break;
    }
    const unsigned u = __float_as_uint(x);
    const float lo = x - __uint_as_float(u & 0xFFFF0000u);
    const int o = seg * 16384 + e;
    ph[o] = (unsigned short)(u >> 16);
    pl[o] = (unsigned short)(__float_as_uint(lo) >> 16);
}

// ================= MFMA split-bf16 GEMM (128 nodes x 128 cols / block) =================
// NW=1: one weight set. NW=2: block sequentially processes two weight sets
// (Bh/Bl and Bh2/Bl2) against the SAME A tile -> second pass hits L2 (same XCD).
template<int NW>
__global__ __launch_bounds__(256) void gemm_mfma(
    const float* __restrict__ in,
    const unsigned short* __restrict__ Bh, const unsigned short* __restrict__ Bl,
    float* __restrict__ out0, const float* __restrict__ bias0, int os0, int obf0,
    float* __restrict__ out1, const float* __restrict__ bias1, int os1, int obf1,
    int relu,
    const unsigned short* Bh2, const unsigned short* Bl2,
    float* out0b, const float* bias0b, int os0b, int obf0b,
    float* out1b, const float* bias1b, int os1b, int obf1b,
    int relub) {
    const int t = threadIdx.x;
    const int lane = t & 63;
    const int wid = t >> 6;
    const int wn = wid & 1;
    const int wc = wid >> 1;
    const int l15 = lane & 15;
    const int lk = lane >> 4;
    const int nb = (int)blockIdx.x * 128 + wn * 64;

    const float* arow[4];
#pragma unroll
    for (int mi = 0; mi < 4; ++mi) {
        int r = nb + mi * 16 + l15;
        if (r > NN - 1) r = NN - 1;
        arow[mi] = in + (size_t)r * 128;
    }

#pragma unroll 1
    for (int wsel = 0; wsel < NW; ++wsel) {
        const unsigned short* BhS = wsel ? Bh2 : Bh;
        const unsigned short* BlS = wsel ? Bl2 : Bl;
        float* const outp = wsel ? (wc ? out1b : out0b) : (wc ? out1 : out0);
        const float* const biasp = wsel ? (wc ? bias1b : bias0b) : (wc ? bias1 : bias0);
        const int os = wsel ? (wc ? os1b : os0b) : (wc ? os1 : os0);
        const int obf = wsel ? (wc ? obf1b : obf0b) : (wc ? obf1 : obf0);
        const int rel = wsel ? relub : relu;
        const unsigned short* const Bhp = BhS + (size_t)(wc * 64) * 128;
        const unsigned short* const Blp = BlS + (size_t)(wc * 64) * 128;
        const ptrdiff_t dlo = Blp - Bhp;

        float4v acc[4][4];
#pragma unroll
        for (int mi = 0; mi < 4; ++mi)
#pragma unroll
            for (int ci = 0; ci < 4; ++ci) acc[mi][ci] = (float4v)0.0f;

        const unsigned short* brow[4];
#pragma unroll
        for (int ci = 0; ci < 4; ++ci) brow[ci] = Bhp + (size_t)(ci * 16 + l15) * 128;

        for (int ks = 0; ks < 4; ++ks) {
            const int ko = ks * 32 + lk * 8;
            short8v Ah[4], Al[4];
#pragma unroll
            for (int mi = 0; mi < 4; ++mi) {
                const float4v v0 = *reinterpret_cast<const float4v*>(arow[mi] + ko);
                const float4v v1 = *reinterpret_cast<const float4v*>(arow[mi] + ko + 4);
                float xv[8] = {v0.x, v0.y, v0.z, v0.w, v1.x, v1.y, v1.z, v1.w};
                union { unsigned u[4]; short8v s; } H, L;
#pragma unroll
                for (int q = 0; q < 4; ++q) {
                    const unsigned u0 = __float_as_uint(xv[2 * q]);
                    const unsigned u1 = __float_as_uint(xv[2 * q + 1]);
                    const float l0 = xv[2 * q]     - __uint_as_float(u0 & 0xFFFF0000u);
                    const float l1 = xv[2 * q + 1] - __uint_as_float(u1 & 0xFFFF0000u);
                    H.u[q] = (u1 & 0xFFFF0000u) | (u0 >> 16);
                    L.u[q] = (__float_as_uint(l1) & 0xFFFF0000u) | (__float_as_uint(l0) >> 16);
                }
                Ah[mi] = H.s;
                Al[mi] = L.s;
            }
            short8v Bhf[4], Blf[4];
#pragma unroll
            for (int ci = 0; ci < 4; ++ci) {
                Bhf[ci] = *reinterpret_cast<const short8v*>(brow[ci] + ko);
                Blf[ci] = *reinterpret_cast<const short8v*>(brow[ci] + dlo + ko);
            }
#pragma unroll
            for (int mi = 0; mi < 4; ++mi)
#pragma unroll
                for (int ci = 0; ci < 4; ++ci) {
                    acc[mi][ci] = __builtin_amdgcn_mfma_f32_16x16x32_bf16(Ah[mi], Bhf[ci], acc[mi][ci], 0, 0, 0);
                    acc[mi][ci] = __builtin_amdgcn_mfma_f32_16x16x32_bf16(Ah[mi], Blf[ci], acc[mi][ci], 0, 0, 0);
                    acc[mi][ci] = __builtin_amdgcn_mfma_f32_16x16x32_bf16(Al[mi], Bhf[ci], acc[mi][ci], 0, 0, 0);
                }
        }

#pragma unroll
        for (int ci = 0; ci < 4; ++ci) {
            const int c = ci * 16 + l15;
            const float b = biasp ? biasp[c] : 0.0f;
#pragma unroll
            for (int mi = 0; mi < 4; ++mi) {
#pragma unroll
                for (int j = 0; j < 4; ++j) {
                    const int r = nb + mi * 16 + lk * 4 + j;
                    if (r < NN) {
                        float v = acc[mi][ci][j] + b;
                        if (rel) v = fmaxf(v, 0.0f);
                        if (obf) ((unsigned short*)outp)[(size_t)r * os + c] = f2bf(v);
                        else outp[(size_t)r * os + c] = v;
                    }
                }
            }
        }
    }
}

extern "C" void kernel_launch(void* const* d_in, const int* in_sizes, int n_in,
                              void* d_out, int out_size, void* d_ws, size_t ws_size,
                              hipStream_t stream) {
    const float* x   = (const float*)d_in[0];
    const int*   eix = (const int*)d_in[1];
    const float* Wl1 = (const float*)d_in[2];
    const float* bl1 = (const float*)d_in[3];
    const float* Wr1 = (const float*)d_in[4];
    const float* Wl2 = (const float*)d_in[5];
    const float* bl2 = (const float*)d_in[6];
    const float* Wr2 = (const float*)d_in[7];
    const float* Wl3 = (const float*)d_in[8];
    const float* bl3 = (const float*)d_in[9];
    const float* Wr3 = (const float*)d_in[10];
    const float* Wl4 = (const float*)d_in[11];
    const float* bl4 = (const float*)d_in[12];
    const float* Wr4 = (const float*)d_in[13];
    float* out = (float*)d_out;

    const int* src = eix;        // edge_index[0]
    const int* dst = eix + NE;   // edge_index[1]

    // workspace layout (R13-proven)
    char* ws = (char*)d_ws;
    int*   cnt  = (int*)ws;                          // [NN]
    int*   off  = cnt + NN;                          // [NN]
    float* inv  = (float*)(off + NN);                // [NN]
    int*   Hs   = (int*)(inv + NN);                  // [HLEN]
    int*   part = Hs + HLEN;                         // [256]
    int*   srcs = part + 256;                        // [NE] int
    unsigned short* ph = (unsigned short*)(srcs + NE);   // [81920]
    unsigned short* pl = ph + 81920;                 // [81920]
    unsigned short* XB1 = pl + 81920;                // [NN*64] bf16 msgs L1
    unsigned short* H1B = XB1 + (size_t)NN * 64;     // [NN*64] bf16 h1
    unsigned short* G3B = XB1;                       // alias [NN*128] bf16 msgs L3
    float* HCAT = (float*)(XB1 + (size_t)NN * 128);  // [NN*128] [mean|h1]; G4B alias
    float* H2   = HCAT + (size_t)NN * 128;           // [NN*128]
    float* HPRE = H2 + (size_t)NN * 128;             // [NN*128] h3pre/h3; tmp alias
    unsigned*       tmp = (unsigned*)HPRE;           // [NE] (CSR build only)
    unsigned short* G4B = (unsigned short*)HCAT;     // [NN*64] bf16 msgs L4

    // ---- radix CSR build ----
    hist_kernel<<<PB, 256, 0, stream>>>(dst, Hs);
    scanA_kernel<<<SAB, 256, 0, stream>>>(Hs, part);
    scanB_kernel<<<1, 128, 0, stream>>>(part);
    scanC_kernel<<<SAB, 256, 0, stream>>>(Hs, part);
    partition_kernel<<<PB, 256, 0, stream>>>(src, dst, Hs, tmp);
    finalize_kernel<<<NBUK, 256, 0, stream>>>(tmp, Hs, off, cnt, inv, srcs);

    // ---- weight bf16 hi/lo planes ----
    {
        WSrc s;
        s.p[0] = Wl1; s.p[1] = Wr1; s.p[2] = Wl2; s.p[3] = Wr2;
        s.p[4] = Wl3; s.p[5] = Wr3; s.p[6] = Wl4; s.p[7] = Wr4;
        wplanes_kernel<<<dim3(64, 5), 256, 0, stream>>>(s, ph, pl);
    }

    // ---- Layer 1: x@[Wl1;Wr1] -> XB1(bf16), h1pre(=HCAT+64 fp32, +bl1) ----
    gemm_mfma<1><<<GB, 256, 0, stream>>>(x, ph, pl,
                                         (float*)XB1, nullptr, 64, 1,
                                         HCAT + 64, bl1, 128, 0, 0,
                                         nullptr, nullptr, nullptr, nullptr, 0, 0,
                                         nullptr, nullptr, 0, 0, 0);
    gather_kernel<64, 1, 1><<<12500, 256, 0, stream>>>(
        XB1, 64, srcs, off, cnt, inv, HCAT + 64, 128, HCAT + 64, 128, H1B);

    // ---- Layer 2: mean(H1B) -> HCAT cols 0..63; [mean|h1]@[Wl2|Wr2] -> H2 (relu) ----
    gather_kernel<64, 0, 0><<<12500, 256, 0, stream>>>(
        H1B, 64, srcs, off, cnt, inv, nullptr, 0, HCAT, 128, nullptr);
    gemm_mfma<1><<<GB, 256, 0, stream>>>(HCAT, ph + 16384, pl + 16384,
                                         H2, bl2, 128, 0,
                                         H2 + 64, bl2 + 64, 128, 0, 1,
                                         nullptr, nullptr, nullptr, nullptr, 0, 0,
                                         nullptr, nullptr, 0, 0, 0);

    // ---- Layer 3 (block-sequential dual): h2@Wl3 -> G3B (bf16); h2@Wr3+bl3 -> HPRE ----
    gemm_mfma<2><<<GB, 256, 0, stream>>>(H2, ph + 2 * 16384, pl + 2 * 16384,
                                         (float*)G3B, nullptr, 128, 1,
                                         (float*)(G3B + 64), nullptr, 128, 1, 0,
                                         ph + 3 * 16384, pl + 3 * 16384,
                                         HPRE, bl3, 128, 0,
                                         HPRE + 64, bl3 + 64, 128, 0, 0);
    gather_kernel<128, 1, 0><<<12500, 256, 0, stream>>>(
        G3B, 128, srcs, off, cnt, inv, HPRE, 128, HPRE, 128, nullptr);

    // ---- Layer 4: h3@Wl4 -> G4B (bf16); h3@Wr4+bl4 -> d_out; gather -> out ----
    gemm_mfma<1><<<GB, 256, 0, stream>>>(HPRE, ph + 4 * 16384, pl + 4 * 16384,
                                         (float*)G4B, nullptr, 64, 1,
                                         out, bl4, 64, 0, 0,
                                         nullptr, nullptr, nullptr, nullptr, 0, 0,
                                         nullptr, nullptr, 0, 0, 0);
    gather_kernel<64, 2, 0><<<12500, 256, 0, stream>>>(
        G4B, 64, srcs, off, cnt, inv, out, 64, out, 64, nullptr);
}

// Round 21
// 323.599 us; speedup vs baseline: 1.3490x; 1.0309x over previous
//
#include <hip/hip_runtime.h>

#define NN 50000
#define NE 800000
#define GB 391     // ceil(NN/128) gemm node-blocks
#define NBUK 196   // dst buckets (dst>>8)
#define PB 128     // partition blocks
#define CH 6250    // edges per partition block (PB*CH == NE)
#define HLEN (NBUK * PB)       // 25088
#define SAB (HLEN / 256)       // 98 scan blocks

typedef __attribute__((ext_vector_type(8))) short short8v;
typedef __attribute__((ext_vector_type(4))) float float4v;

__device__ __forceinline__ int uni(int v) { return __builtin_amdgcn_readfirstlane(v); }
__device__ __forceinline__ unsigned short f2bf(float f) {
    unsigned u = __float_as_uint(f);
    return (unsigned short)((u + 0x7FFFu + ((u >> 16) & 1u)) >> 16);
}
__device__ __forceinline__ float bf2f(unsigned short h) {
    return __uint_as_float(((unsigned)h) << 16);
}

// ================= radix CSR build =================
__global__ __launch_bounds__(256) void hist_kernel(const int* __restrict__ dst,
                                                   int* __restrict__ H) {
    __shared__ int h[NBUK];
    const int t = threadIdx.x;
    const int b = blockIdx.x;
    if (t < NBUK) h[t] = 0;
    __syncthreads();
    const int e0 = b * CH;
    for (int i = t; i < CH; i += 256) {
        int e = e0 + i;
        if (e < NE) atomicAdd(&h[dst[e] >> 8], 1);
    }
    __syncthreads();
    if (t < NBUK) H[t * PB + b] = h[t];
}

__global__ __launch_bounds__(256) void scanA_kernel(const int* __restrict__ a,
                                                    int* __restrict__ part) {
    __shared__ int red[256];
    const int t = threadIdx.x;
    red[t] = a[blockIdx.x * 256 + t];
    __syncthreads();
#pragma unroll
    for (int d = 128; d > 0; d >>= 1) {
        if (t < d) red[t] += red[t + d];
        __syncthreads();
    }
    if (t == 0) part[blockIdx.x] = red[0];
}

__global__ __launch_bounds__(128) void scanB_kernel(int* __restrict__ part) {
    __shared__ int ps[128];
    const int t = threadIdx.x;
    ps[t] = (t < SAB) ? part[t] : 0;
    __syncthreads();
#pragma unroll
    for (int d = 1; d < 128; d <<= 1) {
        int v = (t >= d) ? ps[t - d] : 0;
        __syncthreads();
        ps[t] += v;
        __syncthreads();
    }
    if (t < SAB) part[t] = (t == 0) ? 0 : ps[t - 1];
}

__global__ __launch_bounds__(256) void scanC_kernel(int* __restrict__ a,
                                                    const int* __restrict__ part) {
    __shared__ int ps[256];
    const int t = threadIdx.x;
    const int i = blockIdx.x * 256 + t;
    const int c = a[i];
    ps[t] = c;
    __syncthreads();
#pragma unroll
    for (int d = 1; d < 256; d <<= 1) {
        int v = (t >= d) ? ps[t - d] : 0;
        __syncthreads();
        ps[t] += v;
        __syncthreads();
    }
    a[i] = part[blockIdx.x] + ps[t] - c;   // exclusive
}

__global__ __launch_bounds__(256) void partition_kernel(const int* __restrict__ src,
                                                        const int* __restrict__ dst,
                                                        const int* __restrict__ Hs,
                                                        unsigned* __restrict__ tmp) {
    __shared__ int cur[NBUK];
    const int t = threadIdx.x;
    const int b = blockIdx.x;
    if (t < NBUK) cur[t] = Hs[t * PB + b];
    __syncthreads();
    const int e0 = b * CH;
    for (int i = t; i < CH; i += 256) {
        int e = e0 + i;
        if (e < NE) {
            const int d = dst[e];
            const int k = d >> 8;
            const int pos = atomicAdd(&cur[k], 1);
            tmp[pos] = (unsigned)src[e] | ((unsigned)(d & 255) << 16);
        }
    }
}

__global__ __launch_bounds__(256) void finalize_kernel(const unsigned* __restrict__ tmp,
                                                       const int* __restrict__ Hs,
                                                       int* __restrict__ off,
                                                       int* __restrict__ cnt,
                                                       float* __restrict__ inv,
                                                       int* __restrict__ srcs) {
    __shared__ int hist[256];
    __shared__ int ps[256];
    __shared__ int cur[256];
    const int t = threadIdx.x;
    const int k = blockIdx.x;
    const int s0 = Hs[k * PB];
    const int end = (k == NBUK - 1) ? NE : Hs[(k + 1) * PB];
    const int m = end - s0;
    hist[t] = 0;
    __syncthreads();
    for (int i = t; i < m; i += 256) {
        atomicAdd(&hist[(tmp[s0 + i] >> 16) & 255], 1);
    }
    __syncthreads();
    const int c = hist[t];
    ps[t] = c;
    __syncthreads();
#pragma unroll
    for (int d = 1; d < 256; d <<= 1) {
        int v = (t >= d) ? ps[t - d] : 0;
        __syncthreads();
        ps[t] += v;
        __syncthreads();
    }
    const int ex = ps[t] - c;
    const int node = k * 256 + t;
    if (node < NN) {
        off[node] = s0 + ex;
        cnt[node] = c;
        inv[node] = 1.0f / (float)max(c, 1);
    }
    cur[t] = s0 + ex;
    __syncthreads();
    for (int i = t; i < m; i += 256) {
        const unsigned u = tmp[s0 + i];
        const int p = atomicAdd(&cur[(u >> 16) & 255], 1);
        srcs[p] = (int)(u & 0xFFFFu);
    }
}

// ================= pull-gather mean aggregation (half-wave per edge) =================
// bf16 source tables, fully temporal. Lanes 0-31 even edges, 32-63 odd edges;
// ushort2 (D=64) / ushort4 (D=128) per lane; halves combined via shfl_xor(32).
// MODE: 0 = mean ; 1 = relu(pre + mean) ; 2 = pre + mean. DUALB: extra bf16 copy (D=64).
template<int D, int MODE, int DUALB>
__global__ __launch_bounds__(256) void gather_kernel(
    const unsigned short* __restrict__ yb, int ys, const int* __restrict__ srcs,
    const int* __restrict__ off, const int* __restrict__ cnt,
    const float* __restrict__ inv, const float* __restrict__ pre, int ps,
    float* __restrict__ out, int os, unsigned short* __restrict__ outb) {
    const int w = (blockIdx.x * blockDim.x + threadIdx.x) >> 6;
    const int lane = threadIdx.x & 63;
    if (w >= NN) return;
    const int o = uni(off[w]);
    const int n = uni(cnt[w]);
    const int h = lane >> 5;       // half-wave id
    const int l = lane & 31;

    float a0 = 0.0f, a1 = 0.0f, a2 = 0.0f, a3 = 0.0f;
    int i = 0;
    for (; i + 8 <= n; i += 8) {
        int e0 = srcs[o + i + h];
        int e1 = srcs[o + i + 2 + h];
        int e2 = srcs[o + i + 4 + h];
        int e3 = srcs[o + i + 6 + h];
        if constexpr (D == 64) {
            const ushort2 v0 = *reinterpret_cast<const ushort2*>(&yb[(size_t)e0 * ys + 2 * l]);
            const ushort2 v1 = *reinterpret_cast<const ushort2*>(&yb[(size_t)e1 * ys + 2 * l]);
            const ushort2 v2 = *reinterpret_cast<const ushort2*>(&yb[(size_t)e2 * ys + 2 * l]);
            const ushort2 v3 = *reinterpret_cast<const ushort2*>(&yb[(size_t)e3 * ys + 2 * l]);
            a0 += bf2f(v0.x) + bf2f(v1.x) + bf2f(v2.x) + bf2f(v3.x);
            a1 += bf2f(v0.y) + bf2f(v1.y) + bf2f(v2.y) + bf2f(v3.y);
        } else {
            const ushort4 v0 = *reinterpret_cast<const ushort4*>(&yb[(size_t)e0 * ys + 4 * l]);
            const ushort4 v1 = *reinterpret_cast<const ushort4*>(&yb[(size_t)e1 * ys + 4 * l]);
            const ushort4 v2 = *reinterpret_cast<const ushort4*>(&yb[(size_t)e2 * ys + 4 * l]);
            const ushort4 v3 = *reinterpret_cast<const ushort4*>(&yb[(size_t)e3 * ys + 4 * l]);
            a0 += bf2f(v0.x) + bf2f(v1.x) + bf2f(v2.x) + bf2f(v3.x);
            a1 += bf2f(v0.y) + bf2f(v1.y) + bf2f(v2.y) + bf2f(v3.y);
            a2 += bf2f(v0.z) + bf2f(v1.z) + bf2f(v2.z) + bf2f(v3.z);
            a3 += bf2f(v0.w) + bf2f(v1.w) + bf2f(v2.w) + bf2f(v3.w);
        }
    }
    for (; i + 2 <= n; i += 2) {
        int e = srcs[o + i + h];
        if constexpr (D == 64) {
            const ushort2 v = *reinterpret_cast<const ushort2*>(&yb[(size_t)e * ys + 2 * l]);
            a0 += bf2f(v.x);
            a1 += bf2f(v.y);
        } else {
            const ushort4 v = *reinterpret_cast<const ushort4*>(&yb[(size_t)e * ys + 4 * l]);
            a0 += bf2f(v.x); a1 += bf2f(v.y); a2 += bf2f(v.z); a3 += bf2f(v.w);
        }
    }
    if (i < n && h == 0) {
        int e = srcs[o + i];
        if constexpr (D == 64) {
            const ushort2 v = *reinterpret_cast<const ushort2*>(&yb[(size_t)e * ys + 2 * l]);
            a0 += bf2f(v.x);
            a1 += bf2f(v.y);
        } else {
            const ushort4 v = *reinterpret_cast<const ushort4*>(&yb[(size_t)e * ys + 4 * l]);
            a0 += bf2f(v.x); a1 += bf2f(v.y); a2 += bf2f(v.z); a3 += bf2f(v.w);
        }
    }
    // combine halves
    a0 += __shfl_xor(a0, 32, 64);
    a1 += __shfl_xor(a1, 32, 64);
    if constexpr (D == 128) {
        a2 += __shfl_xor(a2, 32, 64);
        a3 += __shfl_xor(a3, 32, 64);
    }
    if (h != 0) return;

    const float iv = inv[w];
    if constexpr (D == 64) {
        float r0 = a0 * iv, r1 = a1 * iv;
        if constexpr (MODE != 0) {
            const float2 pv = *reinterpret_cast<const float2*>(&pre[(size_t)w * ps + 2 * l]);
            r0 += pv.x; r1 += pv.y;
        }
        if constexpr (MODE == 1) { r0 = fmaxf(r0, 0.0f); r1 = fmaxf(r1, 0.0f); }
        float2 sv = {r0, r1};
        *reinterpret_cast<float2*>(&out[(size_t)w * os + 2 * l]) = sv;
        if constexpr (DUALB) {
            ushort2 bv = {f2bf(r0), f2bf(r1)};
            *reinterpret_cast<ushort2*>(&outb[(size_t)w * 64 + 2 * l]) = bv;
        }
    } else {
        float r0 = a0 * iv, r1 = a1 * iv, r2 = a2 * iv, r3 = a3 * iv;
        if constexpr (MODE != 0) {
            const float4 pv = *reinterpret_cast<const float4*>(&pre[(size_t)w * ps + 4 * l]);
            r0 += pv.x; r1 += pv.y; r2 += pv.z; r3 += pv.w;
        }
        if constexpr (MODE == 1) {
            r0 = fmaxf(r0, 0.0f); r1 = fmaxf(r1, 0.0f);
            r2 = fmaxf(r2, 0.0f); r3 = fmaxf(r3, 0.0f);
        }
        float4 sv = {r0, r1, r2, r3};
        *reinterpret_cast<float4*>(&out[(size_t)w * os + 4 * l]) = sv;
    }
}

// ================= weight planes: fp32 -> bf16 hi/lo =================
struct WSrc { const float* p[8]; };

__global__ __launch_bounds__(256) void wplanes_kernel(WSrc S,
                                                      unsigned short* __restrict__ ph,
                                                      unsigned short* __restrict__ pl) {
    const int e = blockIdx.x * 256 + threadIdx.x;   // 0..16383
    const int seg = blockIdx.y;
    const int row = e >> 7, k = e & 127;
    float x;
    switch (seg) {
        case 0:  x = (row < 64) ? S.p[0][row * 128 + k] : S.p[1][(row - 64) * 128 + k]; break;
        case 1:  x = (k < 64)   ? S.p[2][row * 64 + k]  : S.p[3][row * 64 + (k - 64)];  break;
        case 2:  x = S.p[4][e]; break;
        case 3:  x = S.p[5][e]; break;
        default: x = (row < 64) ? S.p[6][row * 128 + k] : S.p[7][(row - 64) * 128 + k]; break;
    }
    const unsigned u = __float_as_uint(x);
    const float lo = x - __uint_as_float(u & 0xFFFF0000u);
    const int o = seg * 16384 + e;
    ph[o] = (unsigned short)(u >> 16);
    pl[o] = (unsigned short)(__float_as_uint(lo) >> 16);
}

// ================= MFMA split-bf16 GEMM (128 nodes x 128 cols / block) =================
// R12/R13-proven geometry: 4 waves (2 node-halves x 2 col-halves), 4x4 frags of
// 16x16x32_bf16, 3 precision terms (AhBh + AhBl + AlBh). No LDS, fully temporal.
__global__ __launch_bounds__(256) void gemm_mfma(
    const float* __restrict__ in,
    const unsigned short* __restrict__ Bh, const unsigned short* __restrict__ Bl,
    float* __restrict__ out0, const float* __restrict__ bias0, int os0, int obf0,
    float* __restrict__ out1, const float* __restrict__ bias1, int os1, int obf1,
    int relu) {
    const int t = threadIdx.x;
    const int lane = t & 63;
    const int wid = t >> 6;
    const int wn = wid & 1;
    const int wc = wid >> 1;
    const int l15 = lane & 15;
    const int lk = lane >> 4;
    const int nb = (int)blockIdx.x * 128 + wn * 64;

    float* const outp = wc ? out1 : out0;
    const float* const biasp = wc ? bias1 : bias0;
    const int os = wc ? os1 : os0;
    const int obf = wc ? obf1 : obf0;
    const unsigned short* const Bhp = Bh + (size_t)(wc * 64) * 128;
    const unsigned short* const Blp = Bl + (size_t)(wc * 64) * 128;
    const ptrdiff_t dlo = Blp - Bhp;

    float4v acc[4][4];
#pragma unroll
    for (int mi = 0; mi < 4; ++mi)
#pragma unroll
        for (int ci = 0; ci < 4; ++ci) acc[mi][ci] = (float4v)0.0f;

    const float* arow[4];
#pragma unroll
    for (int mi = 0; mi < 4; ++mi) {
        int r = nb + mi * 16 + l15;
        if (r > NN - 1) r = NN - 1;
        arow[mi] = in + (size_t)r * 128;
    }
    const unsigned short* brow[4];
#pragma unroll
    for (int ci = 0; ci < 4; ++ci) brow[ci] = Bhp + (size_t)(ci * 16 + l15) * 128;

    for (int ks = 0; ks < 4; ++ks) {
        const int ko = ks * 32 + lk * 8;
        short8v Ah[4], Al[4];
#pragma unroll
        for (int mi = 0; mi < 4; ++mi) {
            const float4v v0 = *reinterpret_cast<const float4v*>(arow[mi] + ko);
            const float4v v1 = *reinterpret_cast<const float4v*>(arow[mi] + ko + 4);
            float xv[8] = {v0.x, v0.y, v0.z, v0.w, v1.x, v1.y, v1.z, v1.w};
            union { unsigned u[4]; short8v s; } H, L;
#pragma unroll
            for (int q = 0; q < 4; ++q) {
                const unsigned u0 = __float_as_uint(xv[2 * q]);
                const unsigned u1 = __float_as_uint(xv[2 * q + 1]);
                const float l0 = xv[2 * q]     - __uint_as_float(u0 & 0xFFFF0000u);
                const float l1 = xv[2 * q + 1] - __uint_as_float(u1 & 0xFFFF0000u);
                H.u[q] = (u1 & 0xFFFF0000u) | (u0 >> 16);
                L.u[q] = (__float_as_uint(l1) & 0xFFFF0000u) | (__float_as_uint(l0) >> 16);
            }
            Ah[mi] = H.s;
            Al[mi] = L.s;
        }
        short8v Bhf[4], Blf[4];
#pragma unroll
        for (int ci = 0; ci < 4; ++ci) {
            Bhf[ci] = *reinterpret_cast<const short8v*>(brow[ci] + ko);
            Blf[ci] = *reinterpret_cast<const short8v*>(brow[ci] + dlo + ko);
        }
#pragma unroll
        for (int mi = 0; mi < 4; ++mi)
#pragma unroll
            for (int ci = 0; ci < 4; ++ci) {
                acc[mi][ci] = __builtin_amdgcn_mfma_f32_16x16x32_bf16(Ah[mi], Bhf[ci], acc[mi][ci], 0, 0, 0);
                acc[mi][ci] = __builtin_amdgcn_mfma_f32_16x16x32_bf16(Ah[mi], Blf[ci], acc[mi][ci], 0, 0, 0);
                acc[mi][ci] = __builtin_amdgcn_mfma_f32_16x16x32_bf16(Al[mi], Bhf[ci], acc[mi][ci], 0, 0, 0);
            }
    }

#pragma unroll
    for (int ci = 0; ci < 4; ++ci) {
        const int c = ci * 16 + l15;
        const float b = biasp ? biasp[c] : 0.0f;
#pragma unroll
        for (int mi = 0; mi < 4; ++mi) {
#pragma unroll
            for (int j = 0; j < 4; ++j) {
                const int r = nb + mi * 16 + lk * 4 + j;
                if (r < NN) {
                    float v = acc[mi][ci][j] + b;
                    if (relu) v = fmaxf(v, 0.0f);
                    if (obf) ((unsigned short*)outp)[(size_t)r * os + c] = f2bf(v);
                    else outp[(size_t)r * os + c] = v;
                }
            }
        }
    }
}

extern "C" void kernel_launch(void* const* d_in, const int* in_sizes, int n_in,
                              void* d_out, int out_size, void* d_ws, size_t ws_size,
                              hipStream_t stream) {
    const float* x   = (const float*)d_in[0];
    const int*   eix = (const int*)d_in[1];
    const float* Wl1 = (const float*)d_in[2];
    const float* bl1 = (const float*)d_in[3];
    const float* Wr1 = (const float*)d_in[4];
    const float* Wl2 = (const float*)d_in[5];
    const float* bl2 = (const float*)d_in[6];
    const float* Wr2 = (const float*)d_in[7];
    const float* Wl3 = (const float*)d_in[8];
    const float* bl3 = (const float*)d_in[9];
    const float* Wr3 = (const float*)d_in[10];
    const float* Wl4 = (const float*)d_in[11];
    const float* bl4 = (const float*)d_in[12];
    const float* Wr4 = (const float*)d_in[13];
    float* out = (float*)d_out;

    const int* src = eix;        // edge_index[0]
    const int* dst = eix + NE;   // edge_index[1]

    // workspace layout
    char* ws = (char*)d_ws;
    int*   cnt  = (int*)ws;                          // [NN]
    int*   off  = cnt + NN;                          // [NN]
    float* inv  = (float*)(off + NN);                // [NN]
    int*   Hs   = (int*)(inv + NN);                  // [HLEN]
    int*   part = Hs + HLEN;                         // [256]
    int*   srcs = part + 256;                        // [NE]
    unsigned short* ph = (unsigned short*)(srcs + NE);   // [81920]
    unsigned short* pl = ph + 81920;                 // [81920]
    unsigned short* XB1 = pl + 81920;                // [NN*64] bf16 msgs L1
    unsigned short* H1B = XB1 + (size_t)NN * 64;     // [NN*64] bf16 h1
    unsigned short* G3B = XB1;                       // alias [NN*128] bf16 msgs L3
    float* HCAT = (float*)(XB1 + (size_t)NN * 128);  // [NN*128] [mean|h1]; G4B alias
    float* H2   = HCAT + (size_t)NN * 128;           // [NN*128]
    float* HPRE = H2 + (size_t)NN * 128;             // [NN*128] h3pre/h3; tmp alias
    unsigned*       tmp = (unsigned*)HPRE;           // [NE] (CSR build only)
    unsigned short* G4B = (unsigned short*)HCAT;     // [NN*64] bf16 msgs L4

    // ---- radix CSR build ----
    hist_kernel<<<PB, 256, 0, stream>>>(dst, Hs);
    scanA_kernel<<<SAB, 256, 0, stream>>>(Hs, part);
    scanB_kernel<<<1, 128, 0, stream>>>(part);
    scanC_kernel<<<SAB, 256, 0, stream>>>(Hs, part);
    partition_kernel<<<PB, 256, 0, stream>>>(src, dst, Hs, tmp);
    finalize_kernel<<<NBUK, 256, 0, stream>>>(tmp, Hs, off, cnt, inv, srcs);

    // ---- weight bf16 hi/lo planes ----
    {
        WSrc s;
        s.p[0] = Wl1; s.p[1] = Wr1; s.p[2] = Wl2; s.p[3] = Wr2;
        s.p[4] = Wl3; s.p[5] = Wr3; s.p[6] = Wl4; s.p[7] = Wr4;
        wplanes_kernel<<<dim3(64, 5), 256, 0, stream>>>(s, ph, pl);
    }

    // ---- Layer 1: x@[Wl1;Wr1] -> XB1(bf16), h1pre(=HCAT+64 fp32, +bl1) ----
    gemm_mfma<<<GB, 256, 0, stream>>>(x, ph, pl,
                                      (float*)XB1, nullptr, 64, 1,
                                      HCAT + 64, bl1, 128, 0, 0);
    gather_kernel<64, 1, 1><<<12500, 256, 0, stream>>>(
        XB1, 64, srcs, off, cnt, inv, HCAT + 64, 128, HCAT + 64, 128, H1B);

    // ---- Layer 2: mean(H1B) -> HCAT cols 0..63; [mean|h1]@[Wl2|Wr2] -> H2 (relu) ----
    gather_kernel<64, 0, 0><<<12500, 256, 0, stream>>>(
        H1B, 64, srcs, off, cnt, inv, nullptr, 0, HCAT, 128, nullptr);
    gemm_mfma<<<GB, 256, 0, stream>>>(HCAT, ph + 16384, pl + 16384,
                                      H2, bl2, 128, 0,
                                      H2 + 64, bl2 + 64, 128, 0, 1);

    // ---- Layer 3: h2@Wl3 -> G3B (bf16); h2@Wr3+bl3 -> h3pre(=HPRE fp32) ----
    gemm_mfma<<<GB, 256, 0, stream>>>(H2, ph + 2 * 16384, pl + 2 * 16384,
                                      (float*)G3B, nullptr, 128, 1,
                                      (float*)(G3B + 64), nullptr, 128, 1, 0);
    gemm_mfma<<<GB, 256, 0, stream>>>(H2, ph + 3 * 16384, pl + 3 * 16384,
                                      HPRE, bl3, 128, 0,
                                      HPRE + 64, bl3 + 64, 128, 0, 0);
    gather_kernel<128, 1, 0><<<12500, 256, 0, stream>>>(
        G3B, 128, srcs, off, cnt, inv, HPRE, 128, HPRE, 128, nullptr);

    // ---- Layer 4: h3@Wl4 -> G4B (bf16); h3@Wr4+bl4 -> d_out; gather -> out ----
    gemm_mfma<<<GB, 256, 0, stream>>>(HPRE, ph + 4 * 16384, pl + 4 * 16384,
                                      (float*)G4B, nullptr, 64, 1,
                                      out, bl4, 64, 0, 0);
    gather_kernel<64, 2, 0><<<12500, 256, 0, stream>>>(
        G4B, 64, srcs, off, cnt, inv, out, 64, out, 64, nullptr);
}